// Round 1
// baseline (1672.063 us; speedup 1.0000x reference)
//
#include <hip/hip_runtime.h>
#include <hip/hip_bf16.h>

#define T_TOK 1024
#define H_DIM 2048
#define E_NUM 32
#define F_DIM 1408
#define G_NUM 8
#define TOPKG 3
#define TOPK  6
#define FS_DIM 2816
#define SCALE_F 16.0f

#define BM 128
#define BK 32
#define LDP 40  // padded LDS k-stride (elements)

typedef __attribute__((ext_vector_type(8))) __bf16 bf16x8;
typedef __attribute__((ext_vector_type(4))) float f32x4;

__device__ __forceinline__ unsigned short f2bf(float f) {
    union { float f; unsigned u; } v; v.f = f;
    unsigned r = v.u + 0x7fffu + ((v.u >> 16) & 1u);
    return (unsigned short)(r >> 16);
}

__device__ __forceinline__ bf16x8 ld_frag(const unsigned short* p) {
    union { uint4 u; bf16x8 v; } x;
    x.u = *(const uint4*)p;
    return x.v;
}

__device__ __forceinline__ f32x4 mfma16(bf16x8 a, bf16x8 b, f32x4 c) {
    return __builtin_amdgcn_mfma_f32_16x16x32_bf16(a, b, c, 0, 0, 0);
}

// ---------------- prep: zero counters + convert x to bf16 ----------------
__global__ void prep_kernel(const float* __restrict__ x, unsigned short* __restrict__ xb,
                            int* __restrict__ cnt, int* __restrict__ cnt2) {
    if (blockIdx.x == 0) {
        if (threadIdx.x < E_NUM) cnt[threadIdx.x] = 0;
        else if (threadIdx.x < 2 * E_NUM) cnt2[threadIdx.x - E_NUM] = 0;
    }
    int i = blockIdx.x * blockDim.x + threadIdx.x;  // over T*H/4
    float4 v = ((const float4*)x)[i];
    uint2 o;
    o.x = (unsigned)f2bf(v.x) | ((unsigned)f2bf(v.y) << 16);
    o.y = (unsigned)f2bf(v.z) | ((unsigned)f2bf(v.w) << 16);
    ((uint2*)xb)[i] = o;
}

// ---------------- router: logits + softmax + grouped topk ----------------
__global__ void router_kernel(const float* __restrict__ x, const float* __restrict__ wg,
                              float* __restrict__ topk_w, int* __restrict__ topk_ids,
                              int* __restrict__ cnt) {
    int t = blockIdx.x;
    __shared__ float xs[H_DIM];
    __shared__ float logits[E_NUM];
    const float* xr = x + (size_t)t * H_DIM;
    for (int i = threadIdx.x; i < H_DIM / 4; i += 256)
        ((float4*)xs)[i] = ((const float4*)xr)[i];
    __syncthreads();
    int wave = threadIdx.x >> 6, lane = threadIdx.x & 63;
    for (int eo = 0; eo < 8; ++eo) {
        int e = wave * 8 + eo;
        const float* w = wg + (size_t)e * H_DIM;
        float s = 0.f;
        for (int i = lane; i < H_DIM; i += 64) s += xs[i] * w[i];
        for (int d = 32; d; d >>= 1) s += __shfl_down(s, d);
        if (lane == 0) logits[e] = s;
    }
    __syncthreads();
    if (threadIdx.x == 0) {
        float sc[E_NUM];
        float mx = -1e30f;
        for (int e = 0; e < E_NUM; ++e) mx = fmaxf(mx, logits[e]);
        float sum = 0.f;
        for (int e = 0; e < E_NUM; ++e) { sc[e] = expf(logits[e] - mx); sum += sc[e]; }
        float inv = 1.0f / sum;
        for (int e = 0; e < E_NUM; ++e) sc[e] *= inv;
        float gs[G_NUM];
        for (int g = 0; g < G_NUM; ++g) {
            float m = sc[g * 4];
            for (int j = 1; j < 4; ++j) m = fmaxf(m, sc[g * 4 + j]);
            gs[g] = m;
        }
        unsigned gmask = 0;
        for (int r = 0; r < TOPKG; ++r) {
            int best = 0; float bv = -1e30f;
            for (int g = 0; g < G_NUM; ++g)
                if (!((gmask >> g) & 1) && gs[g] > bv) { bv = gs[g]; best = g; }
            gmask |= 1u << best;
        }
        for (int e = 0; e < E_NUM; ++e)
            if (!((gmask >> (e >> 2)) & 1)) sc[e] = -1.0f;  // scores>0, so -1 never selected
        for (int r = 0; r < TOPK; ++r) {
            int best = 0; float bv = -1e30f;
            for (int e = 0; e < E_NUM; ++e)
                if (sc[e] > bv) { bv = sc[e]; best = e; }
            topk_w[t * TOPK + r] = bv;
            topk_ids[t * TOPK + r] = best;
            sc[best] = -2.0f;
            atomicAdd(&cnt[best], 1);
        }
    }
}

// ---------------- scan ----------------
__global__ void scan_kernel(const int* __restrict__ cnt, int* __restrict__ off) {
    if (threadIdx.x == 0) {
        int a = 0;
        for (int e = 0; e < E_NUM; ++e) { off[e] = a; a += cnt[e]; }
        off[E_NUM] = a;
    }
}

// ---------------- scatter ----------------
__global__ void scatter_kernel(const int* __restrict__ topk_ids, const float* __restrict__ topk_w,
                               const int* __restrict__ off, int* __restrict__ cnt2,
                               int* __restrict__ perm_token, float* __restrict__ perm_w,
                               int* __restrict__ dest) {
    int i = blockIdx.x * blockDim.x + threadIdx.x;
    if (i >= T_TOK * TOPK) return;
    int t = i / TOPK;
    int e = topk_ids[i];
    float w = topk_w[i];
    int pos = off[e] + atomicAdd(&cnt2[e], 1);
    perm_token[pos] = t;
    perm_w[pos] = w * SCALE_F;
    dest[pos] = i;
}

// ---------------- gate_up GEMM with fused SiLU*mul ----------------
// Block tile: 128 rows x (64 left cols + 64 right cols), K-step 32.
// Wave wv: wm=wv>>1 (m half), wn=wv&1 (n half).
template<bool ROUTED>
__global__ __launch_bounds__(256, 2)
void gate_up_kernel(const unsigned short* __restrict__ xb, const float* __restrict__ Bw,
                    unsigned short* __restrict__ act, const int* __restrict__ perm_token,
                    const int* __restrict__ off, int N2, int Fdim) {
    int e = ROUTED ? blockIdx.z : 0;
    int s0 = 0, M = T_TOK;
    if (ROUTED) { s0 = off[e]; M = off[e + 1] - s0; }
    int mbase = blockIdx.y * BM;
    if (mbase >= M) return;
    int nb = blockIdx.x * 64;
    const float* Bp = Bw + (size_t)e * H_DIM * N2;

    __shared__ unsigned short As[BM * LDP];
    __shared__ unsigned short Bs[128 * LDP];

    int tid = threadIdx.x;
    int lane = tid & 63;
    int wv = tid >> 6;
    int wm = wv >> 1, wn = wv & 1;
    int quad = lane >> 4;
    int l16 = lane & 15;

    f32x4 acc[4][4];
#pragma unroll
    for (int i = 0; i < 4; ++i)
#pragma unroll
        for (int j = 0; j < 4; ++j) acc[i][j] = (f32x4){0.f, 0.f, 0.f, 0.f};

    int ar = tid >> 2;      // 0..63
    int aseg = tid & 3;
    int bn = tid & 127;
    int bk0 = (tid >> 7) * 16;
    int bcol = (bn < 64) ? (nb + bn) : (nb + Fdim + (bn - 64));

    // precompute A source row tokens for the two staged rows
    int tokA[2];
#pragma unroll
    for (int i = 0; i < 2; ++i) {
        int g = mbase + i * 64 + ar;
        tokA[i] = (g < M) ? (ROUTED ? perm_token[s0 + g] : g) : -1;
    }

    for (int k0 = 0; k0 < H_DIM; k0 += BK) {
        // stage A (bf16, row-major [m][k])
#pragma unroll
        for (int i = 0; i < 2; ++i) {
            int r = i * 64 + ar;
            uint4 v = {0u, 0u, 0u, 0u};
            if (tokA[i] >= 0)
                v = *(const uint4*)(xb + (size_t)tokA[i] * H_DIM + k0 + aseg * 8);
            *(uint4*)(&As[r * LDP + aseg * 8]) = v;
        }
        // stage B: fp32 -> bf16, transposed into [n][k]
        {
            const float* bp = Bp + (size_t)(k0 + bk0) * N2 + bcol;
            float f[16];
#pragma unroll
            for (int j = 0; j < 16; ++j) f[j] = bp[(size_t)j * N2];
            uint4 w0, w1v;
            w0.x = (unsigned)f2bf(f[0]) | ((unsigned)f2bf(f[1]) << 16);
            w0.y = (unsigned)f2bf(f[2]) | ((unsigned)f2bf(f[3]) << 16);
            w0.z = (unsigned)f2bf(f[4]) | ((unsigned)f2bf(f[5]) << 16);
            w0.w = (unsigned)f2bf(f[6]) | ((unsigned)f2bf(f[7]) << 16);
            w1v.x = (unsigned)f2bf(f[8]) | ((unsigned)f2bf(f[9]) << 16);
            w1v.y = (unsigned)f2bf(f[10]) | ((unsigned)f2bf(f[11]) << 16);
            w1v.z = (unsigned)f2bf(f[12]) | ((unsigned)f2bf(f[13]) << 16);
            w1v.w = (unsigned)f2bf(f[14]) | ((unsigned)f2bf(f[15]) << 16);
            *(uint4*)(&Bs[bn * LDP + bk0]) = w0;
            *(uint4*)(&Bs[bn * LDP + bk0 + 8]) = w1v;
        }
        __syncthreads();
        bf16x8 af[4], bfr[4];
#pragma unroll
        for (int i = 0; i < 4; ++i) {
            int m = wm * 64 + i * 16 + l16;
            af[i] = ld_frag(&As[m * LDP + quad * 8]);
        }
#pragma unroll
        for (int j = 0; j < 4; ++j) {
            int n = (j < 2) ? (wn * 32 + j * 16 + l16) : (64 + wn * 32 + (j - 2) * 16 + l16);
            bfr[j] = ld_frag(&Bs[n * LDP + quad * 8]);
        }
#pragma unroll
        for (int i = 0; i < 4; ++i)
#pragma unroll
            for (int j = 0; j < 4; ++j)
                acc[i][j] = mfma16(af[i], bfr[j], acc[i][j]);
        __syncthreads();
    }

    // epilogue: act[row][col] = silu(left) * right  (bf16)
#pragma unroll
    for (int i = 0; i < 4; ++i) {
#pragma unroll
        for (int j = 0; j < 2; ++j) {
            f32x4 aL = acc[i][j], aR = acc[i][j + 2];
            int col = nb + wn * 32 + j * 16 + l16;
#pragma unroll
            for (int r = 0; r < 4; ++r) {
                int row = wm * 64 + i * 16 + quad * 4 + r;
                int g = mbase + row;
                if (g < M) {
                    float L = aL[r];
                    float s = L / (1.0f + __expf(-L));
                    act[(size_t)(s0 + g) * Fdim + col] = f2bf(s * aR[r]);
                }
            }
        }
    }
}

// ---------------- down GEMM ----------------
// ROUTED: out rows scattered via dest[], scaled by perm_w[]; else direct rows.
template<bool ROUTED>
__global__ __launch_bounds__(256, 2)
void down_kernel(const unsigned short* __restrict__ act, const float* __restrict__ Bw,
                 float* __restrict__ outp, const float* __restrict__ perm_w,
                 const int* __restrict__ dest, const int* __restrict__ off, int K) {
    int e = ROUTED ? blockIdx.z : 0;
    int s0 = 0, M = T_TOK;
    if (ROUTED) { s0 = off[e]; M = off[e + 1] - s0; }
    int mbase = blockIdx.y * BM;
    if (mbase >= M) return;
    int nb = blockIdx.x * 128;
    const float* Bp = Bw + (size_t)e * K * H_DIM;

    __shared__ unsigned short As[BM * LDP];
    __shared__ unsigned short Bs[128 * LDP];

    int tid = threadIdx.x;
    int lane = tid & 63;
    int wv = tid >> 6;
    int wm = wv >> 1, wn = wv & 1;
    int quad = lane >> 4;
    int l16 = lane & 15;

    f32x4 acc[4][4];
#pragma unroll
    for (int i = 0; i < 4; ++i)
#pragma unroll
        for (int j = 0; j < 4; ++j) acc[i][j] = (f32x4){0.f, 0.f, 0.f, 0.f};

    int ar = tid >> 2;
    int aseg = tid & 3;
    int bn = tid & 127;
    int bk0 = (tid >> 7) * 16;
    int bcol = nb + bn;

    for (int k0 = 0; k0 < K; k0 += BK) {
#pragma unroll
        for (int i = 0; i < 2; ++i) {
            int r = i * 64 + ar;
            int g = mbase + r;
            uint4 v = {0u, 0u, 0u, 0u};
            if (g < M)
                v = *(const uint4*)(act + (size_t)(s0 + g) * K + k0 + aseg * 8);
            *(uint4*)(&As[r * LDP + aseg * 8]) = v;
        }
        {
            const float* bp = Bp + (size_t)(k0 + bk0) * H_DIM + bcol;
            float f[16];
#pragma unroll
            for (int j = 0; j < 16; ++j) f[j] = bp[(size_t)j * H_DIM];
            uint4 w0, w1v;
            w0.x = (unsigned)f2bf(f[0]) | ((unsigned)f2bf(f[1]) << 16);
            w0.y = (unsigned)f2bf(f[2]) | ((unsigned)f2bf(f[3]) << 16);
            w0.z = (unsigned)f2bf(f[4]) | ((unsigned)f2bf(f[5]) << 16);
            w0.w = (unsigned)f2bf(f[6]) | ((unsigned)f2bf(f[7]) << 16);
            w1v.x = (unsigned)f2bf(f[8]) | ((unsigned)f2bf(f[9]) << 16);
            w1v.y = (unsigned)f2bf(f[10]) | ((unsigned)f2bf(f[11]) << 16);
            w1v.z = (unsigned)f2bf(f[12]) | ((unsigned)f2bf(f[13]) << 16);
            w1v.w = (unsigned)f2bf(f[14]) | ((unsigned)f2bf(f[15]) << 16);
            *(uint4*)(&Bs[bn * LDP + bk0]) = w0;
            *(uint4*)(&Bs[bn * LDP + bk0 + 8]) = w1v;
        }
        __syncthreads();
        bf16x8 af[4], bfr[4];
#pragma unroll
        for (int i = 0; i < 4; ++i) {
            int m = wm * 64 + i * 16 + l16;
            af[i] = ld_frag(&As[m * LDP + quad * 8]);
        }
#pragma unroll
        for (int j = 0; j < 4; ++j) {
            int n = wn * 64 + j * 16 + l16;
            bfr[j] = ld_frag(&Bs[n * LDP + quad * 8]);
        }
#pragma unroll
        for (int i = 0; i < 4; ++i)
#pragma unroll
            for (int j = 0; j < 4; ++j)
                acc[i][j] = mfma16(af[i], bfr[j], acc[i][j]);
        __syncthreads();
    }

#pragma unroll
    for (int i = 0; i < 4; ++i) {
#pragma unroll
        for (int j = 0; j < 4; ++j) {
            int col = nb + wn * 64 + j * 16 + l16;
#pragma unroll
            for (int r = 0; r < 4; ++r) {
                int row = wm * 64 + i * 16 + quad * 4 + r;
                int g = mbase + row;
                if (g < M) {
                    float w = ROUTED ? perm_w[s0 + g] : 1.0f;
                    int drow = ROUTED ? dest[s0 + g] : g;
                    outp[(size_t)drow * H_DIM + col] = acc[i][j][r] * w;
                }
            }
        }
    }
}

// ---------------- combine: out += sum_k partial[t*6+k] ----------------
__global__ void combine_kernel(float* __restrict__ outp, const float* __restrict__ partial) {
    int t = blockIdx.x;
    const float4* p0 = (const float4*)(partial + (size_t)t * TOPK * H_DIM);
    float4* o = (float4*)(outp + (size_t)t * H_DIM);
    for (int i = threadIdx.x; i < H_DIM / 4; i += 256) {
        float4 v = o[i];
#pragma unroll
        for (int k = 0; k < TOPK; ++k) {
            float4 p = p0[(size_t)k * (H_DIM / 4) + i];
            v.x += p.x; v.y += p.y; v.z += p.z; v.w += p.w;
        }
        o[i] = v;
    }
}

extern "C" void kernel_launch(void* const* d_in, const int* in_sizes, int n_in,
                              void* d_out, int out_size, void* d_ws, size_t ws_size,
                              hipStream_t stream) {
    const float* x   = (const float*)d_in[0];
    const float* wg  = (const float*)d_in[1];
    const float* w1  = (const float*)d_in[2];
    const float* w2  = (const float*)d_in[3];
    const float* ws1 = (const float*)d_in[4];
    const float* ws2 = (const float*)d_in[5];
    float* out = (float*)d_out;

    char* p = (char*)d_ws;
    auto alloc = [&](size_t bytes) {
        char* r = p;
        p += (bytes + 255) & ~(size_t)255;
        return r;
    };
    unsigned short* xb      = (unsigned short*)alloc((size_t)T_TOK * H_DIM * 2);
    float*          topk_w  = (float*)alloc((size_t)T_TOK * TOPK * 4);
    int*            topkid  = (int*)alloc((size_t)T_TOK * TOPK * 4);
    int*            cnt     = (int*)alloc(E_NUM * 4);
    int*            cnt2    = (int*)alloc(E_NUM * 4);
    int*            offs    = (int*)alloc((E_NUM + 1) * 4);
    int*            permtok = (int*)alloc((size_t)T_TOK * TOPK * 4);
    float*          permw   = (float*)alloc((size_t)T_TOK * TOPK * 4);
    int*            dest    = (int*)alloc((size_t)T_TOK * TOPK * 4);
    unsigned short* act_r   = (unsigned short*)alloc((size_t)T_TOK * TOPK * F_DIM * 2);
    unsigned short* act_s   = (unsigned short*)alloc((size_t)T_TOK * FS_DIM * 2);
    float*          partial = (float*)alloc((size_t)T_TOK * TOPK * H_DIM * 4);

    prep_kernel<<<(T_TOK * H_DIM / 4) / 256, 256, 0, stream>>>(x, xb, cnt, cnt2);
    router_kernel<<<T_TOK, 256, 0, stream>>>(x, wg, topk_w, topkid, cnt);
    scan_kernel<<<1, 64, 0, stream>>>(cnt, offs);
    scatter_kernel<<<(T_TOK * TOPK + 255) / 256, 256, 0, stream>>>(topkid, topk_w, offs, cnt2,
                                                                   permtok, permw, dest);
    // routed gate_up: act_r = silu_mul(x[perm] @ w1[e])
    gate_up_kernel<true><<<dim3(F_DIM / 64, T_TOK / BM, E_NUM), 256, 0, stream>>>(
        xb, w1, act_r, permtok, offs, 2 * F_DIM, F_DIM);
    // shared gate_up
    gate_up_kernel<false><<<dim3(FS_DIM / 64, T_TOK / BM, 1), 256, 0, stream>>>(
        xb, ws1, act_s, nullptr, nullptr, 2 * FS_DIM, FS_DIM);
    // shared down -> d_out
    down_kernel<false><<<dim3(H_DIM / 128, T_TOK / BM, 1), 256, 0, stream>>>(
        act_s, ws2, out, nullptr, nullptr, nullptr, FS_DIM);
    // routed down -> partial (scaled by topk_w * 16)
    down_kernel<true><<<dim3(H_DIM / 128, T_TOK / BM, E_NUM), 256, 0, stream>>>(
        act_r, w2, partial, permw, dest, offs, F_DIM);
    // combine
    combine_kernel<<<T_TOK, 256, 0, stream>>>(out, partial);
}